// Round 3
// baseline (519.441 us; speedup 1.0000x reference)
//
#include <hip/hip_runtime.h>
#include <hip/hip_bf16.h>

#define B_   8
#define C_   1024
#define HW_  4096
#define NK   21
#define NT   32                      // 128-row tiling: flags + kprop
#define NT2  16                      // 256-row tiling: kgram tiles
#define NTRI2 (NT2 * (NT2 + 1) / 2)  // 136 upper-triangle 256x256 tiles

using bf16 = __hip_bfloat16;
typedef __attribute__((ext_vector_type(4))) float float4_;
typedef __attribute__((ext_vector_type(8))) int int8v;

#define WAITV0() asm volatile("s_waitcnt vmcnt(0)" ::: "memory")
#define FENCE()  asm volatile("" ::: "memory")
#define BARRIER() do { FENCE(); __builtin_amdgcn_s_barrier(); FENCE(); } while (0)

// ---- kernel 1: transpose + fp8-quantize (UNNORMALIZED) + sumsq reduction ----
__global__ __launch_bounds__(256) void ktrans(const float* __restrict__ x4, float* __restrict__ sumsq,
                                              unsigned char* __restrict__ Xq) {
    int b = blockIdx.z, ct = blockIdx.y, jt = blockIdx.x;
    int c0 = ct * 128, j0 = jt * 64;
    int t = threadIdx.x;
    __shared__ float tile[128][65];   // [c][j]
    __shared__ float ssq[64];

    int jl = t & 63, cl = t >> 6;
    if (t < 64) ssq[t] = 0.f;
    __syncthreads();
    float part = 0.f;
#pragma unroll
    for (int cc = 0; cc < 128; cc += 4) {
        float v = x4[((size_t)b * C_ + c0 + cc + cl) * HW_ + j0 + jl];
        tile[cc + cl][jl] = v;
        part = fmaf(v, v, part);
    }
    atomicAdd(&ssq[jl], part);
    __syncthreads();

    int j = t >> 2, q = t & 3;
    int jg = j0 + j;
    unsigned int pk[8];
#pragma unroll
    for (int g = 0; g < 8; ++g) {
        float f0 = tile[q * 32 + g * 4 + 0][j];
        float f1 = tile[q * 32 + g * 4 + 1][j];
        float f2 = tile[q * 32 + g * 4 + 2][j];
        float f3 = tile[q * 32 + g * 4 + 3][j];
        unsigned int r = 0;
        r = __builtin_amdgcn_cvt_pk_fp8_f32(f0, f1, r, false);
        r = __builtin_amdgcn_cvt_pk_fp8_f32(f2, f3, r, true);
        pk[g] = r;
    }
    unsigned char* dst = Xq + ((size_t)b * HW_ + jg) * C_ + c0 + q * 32;
    *(uint4*)(dst)      = make_uint4(pk[0], pk[1], pk[2], pk[3]);
    *(uint4*)(dst + 16) = make_uint4(pk[4], pk[5], pk[6], pk[7]);

    if (t < 64) atomicAdd(&sumsq[b * HW_ + j0 + t], ssq[t]);
}

// ---- kernel 2: symmetric gram, 256x256 tile, 1024 threads = 16 waves (4x4).
// Per-wave output 64x64 -> acc only 64 VGPRs (spill elimination vs the 8-wave
// 128x64 version whose 128-reg acc + 64-reg frags spilled to scratch: round-1/2
// WRITE_SIZE 78-120 MB vs the 16 MB true write footprint).
// K-loop = T3 minimum-2-phase: stage-at-top (1-tile lead), ONE barrier + ONE
// vmcnt(0) per K-tile, compiler-managed lgkmcnt for ds_read->MFMA, setprio
// around compute. 4 waves/SIMD hide ds_read/MFMA dependency latency.
// Epilogue: nontemporal aff stores (write-once; keep per-XCD L2 = the batch's
// 4 MiB Xq slice resident), per-128-quadrant store gating.
__global__ __launch_bounds__(1024, 1) void kgram(const unsigned char* __restrict__ Xq,
                                                 const float* __restrict__ sumsq, bf16* __restrict__ aff,
                                                 float* __restrict__ colsum, int* __restrict__ flags) {
    int lin = blockIdx.x;
    int b = lin & 7;                 // XCD id == batch id (1088 = 8*136 blocks)
    int p = lin >> 3;
    int it = (int)((2.0f * NT2 + 1.0f - sqrtf((2.0f * NT2 + 1.0f) * (2.0f * NT2 + 1.0f) - 8.0f * (float)p)) * 0.5f);
    while (it > 0 && p < it * NT2 - it * (it - 1) / 2) --it;
    while (p >= (it + 1) * NT2 - (it + 1) * it / 2) ++it;
    int jt = it + p - (it * NT2 - it * (it - 1) / 2);

    int i0 = it * 256, j0 = jt * 256;
    int tid = threadIdx.x, w = tid >> 6, l = tid & 63;
    int wr = w >> 2, wc = w & 3;      // 4x4 wave grid; per-wave output 64x64
    int lrow = l & 15, lk = l >> 4;

    __shared__ __align__(16) unsigned char smem[131072];   // buf0{A,B} buf1{A,B} x 32 KiB
    __shared__ int fl4[4];

    const unsigned char* XA = Xq + ((size_t)b * HW_ + i0) * C_;
    const unsigned char* XB = Xq + ((size_t)b * HW_ + j0) * C_;

    // staging: 1024 threads x 4 loads x 16 B = 64 KiB (A panel + B panel)
    int rhi = tid >> 3, sl = tid & 7, gp = sl ^ (rhi & 7);   // XOR pre-swizzle of global src
    const unsigned char* gA = XA + (size_t)rhi * C_ + (gp << 4);
    const unsigned char* gB = XB + (size_t)rhi * C_ + (gp << 4);
    int ldsA = rhi * 128 + (sl << 4);

    auto stg = [&](int bo, int k0) {
#pragma unroll
        for (int q = 0; q < 2; ++q)
            __builtin_amdgcn_global_load_lds(
                (const __attribute__((address_space(1))) void*)(gA + (size_t)q * 128 * C_ + k0),
                (__attribute__((address_space(3))) void*)(smem + bo + q * 16384 + ldsA), 16, 0, 0);
#pragma unroll
        for (int q = 0; q < 2; ++q)
            __builtin_amdgcn_global_load_lds(
                (const __attribute__((address_space(1))) void*)(gB + (size_t)q * 128 * C_ + k0),
                (__attribute__((address_space(3))) void*)(smem + bo + 32768 + q * 16384 + ldsA), 16, 0, 0);
    };

    auto ldfrag = [&](const unsigned char* base, int r) {
        int sw = r & 7;
        uint4 lo = *(const uint4*)(base + r * 128 + (((lk * 2) ^ sw) << 4));
        uint4 hi = *(const uint4*)(base + r * 128 + (((lk * 2 + 1) ^ sw) << 4));
        int8v v; v[0] = lo.x; v[1] = lo.y; v[2] = lo.z; v[3] = lo.w;
        v[4] = hi.x; v[5] = hi.y; v[6] = hi.z; v[7] = hi.w;
        return v;
    };

    float4_ acc[4][4];
#pragma unroll
    for (int m = 0; m < 4; ++m)
#pragma unroll
        for (int n = 0; n < 4; ++n) acc[m][n] = {0.f, 0.f, 0.f, 0.f};

    // prologue: tile 0 -> buf0; drain; sync
    stg(0, 0);
    WAITV0();
    BARRIER();

    for (int t = 0; t < 8; ++t) {
        int bo = (t & 1) * 65536;
        // stage NEXT tile into the other buffer. Safe: previous iteration's
        // trailing barrier guarantees all waves finished reading it.
        if (t < 7) stg(65536 - bo, (t + 1) * 128);

        // compute current tile (compiler inserts lgkmcnt between ds_read & MFMA)
        int8v bv[4];
#pragma unroll
        for (int n = 0; n < 4; ++n) bv[n] = ldfrag(smem + bo + 32768, wc * 64 + n * 16 + lrow);
        __builtin_amdgcn_s_setprio(1);
#pragma unroll
        for (int m = 0; m < 4; ++m) {
            int8v av = ldfrag(smem + bo, wr * 64 + m * 16 + lrow);
#pragma unroll
            for (int n = 0; n < 4; ++n)
                acc[m][n] = __builtin_amdgcn_mfma_scale_f32_16x16x128_f8f6f4(
                    av, bv[n], acc[m][n], 0, 0, 0, 0x7f7f7f7f, 0, 0x7f7f7f7f);
        }
        __builtin_amdgcn_s_setprio(0);

        // drain the 4 loads issued at top (cover = this tile's reads + MFMAs)
        if (t < 7) WAITV0();
        BARRIER();                    // WAR: next iter's stage may overwrite
    }

    // ---- epilogue: deferred normalization rn_i * rn_j ----
    float rnj[4];
#pragma unroll
    for (int n = 0; n < 4; ++n) {
        int j = j0 + wc * 64 + n * 16 + lrow;
        rnj[n] = 1.0f / fmaxf(sqrtf(sumsq[b * HW_ + j]), 1e-12f);
    }
    float rni[4][4];
#pragma unroll
    for (int m = 0; m < 4; ++m)
#pragma unroll
        for (int r = 0; r < 4; ++r) {
            int i = i0 + wr * 64 + m * 16 + lk * 4 + r;
            rni[m][r] = 1.0f / fmaxf(sqrtf(sumsq[b * HW_ + i]), 1e-12f);
        }
    bool any = false;
#pragma unroll
    for (int m = 0; m < 4; ++m)
#pragma unroll
        for (int n = 0; n < 4; ++n)
#pragma unroll
            for (int r = 0; r < 4; ++r) {
                acc[m][n][r] *= rni[m][r] * rnj[n];
                any |= (acc[m][n][r] >= 0.5f);
            }

    // per-128-quadrant flags: wave (wr,wc) lies entirely in quadrant (wr>>1, wc>>1)
    int q4 = (wr >> 1) * 2 + (wc >> 1);
    if (tid < 4) fl4[tid] = 0;
    __syncthreads();
    unsigned long long bal = __ballot(any);
    if (l == 0 && bal != 0ull) atomicOr(&fl4[q4], 1);
    __syncthreads();
    bool mirror = (it != jt);
    if (tid < 4) {
        int qr = tid >> 1, qc = tid & 1;
        flags[(b * NT + (it * 2 + qr)) * NT + (jt * 2 + qc)] = fl4[tid];
        if (mirror) flags[(b * NT + (jt * 2 + qc)) * NT + (it * 2 + qr)] = fl4[tid];
    }

    // per-wave gating on own quadrant flag: skipped quadrants are never read
    // by kprop (flag==0) and contribute exactly 0 to colsum.
    if (fl4[q4]) {
        size_t affb = (size_t)b * HW_ * HW_;
        float rsum[4][4];
#pragma unroll
        for (int m = 0; m < 4; ++m)
#pragma unroll
            for (int r = 0; r < 4; ++r) rsum[m][r] = 0.f;

#pragma unroll
        for (int n = 0; n < 4; ++n) {
            int j = j0 + wc * 64 + n * 16 + lrow;
            float cs = 0.f;
#pragma unroll
            for (int m = 0; m < 4; ++m) {
#pragma unroll
                for (int r = 0; r < 4; ++r) {
                    float v = acc[m][n][r];
                    v = fminf(fmaxf(v, 0.01f), 0.999f);
                    v = (v < 0.5f) ? 0.0f : v;
                    bf16 bb = __float2bfloat16(v);
                    unsigned short us = __builtin_bit_cast(unsigned short, bb);
                    int i = i0 + wr * 64 + m * 16 + lk * 4 + r;
                    __builtin_nontemporal_store(us, (unsigned short*)(aff + affb + (size_t)i * HW_ + j));
                    float bf = __bfloat162float(bb);
                    cs += bf;
                    rsum[m][r] += bf;
                    if (mirror)
                        __builtin_nontemporal_store(us, (unsigned short*)(aff + affb + (size_t)j * HW_ + i));
                }
            }
            cs += __shfl_xor(cs, 16);
            cs += __shfl_xor(cs, 32);
            if (lk == 0) atomicAdd(&colsum[b * HW_ + j], cs);
        }
        if (mirror) {
#pragma unroll
            for (int m = 0; m < 4; ++m) {
#pragma unroll
                for (int r = 0; r < 4; ++r) {
                    float s = rsum[m][r];
                    s += __shfl_xor(s, 1);
                    s += __shfl_xor(s, 2);
                    s += __shfl_xor(s, 4);
                    s += __shfl_xor(s, 8);
                    if (lrow == 0) {
                        int i = i0 + wr * 64 + m * 16 + lk * 4 + r;
                        atomicAdd(&colsum[b * HW_ + i], s);
                    }
                }
            }
        }
    }
}

// ---- kernel 3: out[k][j] = (sum_i lf[k][i]*aff[i][j]) / colsum[j] -----------
__global__ __launch_bounds__(128) void kprop(const float* __restrict__ lf, const bf16* __restrict__ aff,
                                             const int* __restrict__ flags, const float* __restrict__ colsum,
                                             float* __restrict__ outp) {
    int b = blockIdx.y, jt = blockIdx.x;
    int t = threadIdx.x;                 // 128 threads
    int j = jt * 128 + t;
    __shared__ float lfs[NK * 128];
    float acc[NK];
#pragma unroll
    for (int k = 0; k < NK; ++k) acc[k] = 0.f;

    for (int it = 0; it < NT; ++it) {
        if (flags[(b * NT + it) * NT + jt] == 0) continue;   // block-uniform branch
        __syncthreads();
        for (int idx = t; idx < NK * 128; idx += 128)
            lfs[idx] = lf[((size_t)b * NK + (idx >> 7)) * HW_ + it * 128 + (idx & 127)];
        __syncthreads();
        const bf16* ap = aff + ((size_t)b * HW_ + it * 128) * HW_ + j;
        for (int ii = 0; ii < 128; ++ii) {
            float a = __bfloat162float(ap[(size_t)ii * HW_]);
#pragma unroll
            for (int k = 0; k < NK; ++k)
                acc[k] = fmaf(lfs[(k << 7) + ii], a, acc[k]);
        }
    }
    float inv = 1.0f / colsum[b * HW_ + j];
#pragma unroll
    for (int k = 0; k < NK; ++k)
        outp[((size_t)b * NK + k) * HW_ + j] = acc[k] * inv;
}

extern "C" void kernel_launch(void* const* d_in, const int* in_sizes, int n_in,
                              void* d_out, int out_size, void* d_ws, size_t ws_size,
                              hipStream_t stream) {
    const float* x4 = (const float*)d_in[0];
    const float* logits = (const float*)d_in[1];
    float* out = (float*)d_out;

    char* w = (char*)d_ws;
    size_t off = 0;
    auto take = [&](size_t bytes) {
        char* p = w + off;
        off += (bytes + 255) & ~(size_t)255;
        return p;
    };
    unsigned char* Xq = (unsigned char*)take((size_t)B_ * HW_ * C_);    // 32 MiB
    bf16* aff     = (bf16*)take((size_t)B_ * HW_ * HW_ * 2);            // 256 MiB
    float* colsum = (float*)take((size_t)B_ * HW_ * 4);
    int*   flags  = (int*)take((size_t)B_ * NT * NT * 4);
    float* sumsq  = (float*)take((size_t)B_ * HW_ * 4);
    float* lf1    = (float*)take((size_t)B_ * NK * HW_ * 4);

    hipMemsetAsync(colsum, 0,
                   (size_t)B_ * HW_ * 4 + (size_t)B_ * NT * NT * 4 + (size_t)B_ * HW_ * 4, stream);

    ktrans<<<dim3(HW_ / 64, C_ / 128, B_), dim3(256), 0, stream>>>(x4, sumsq, Xq);
    kgram <<<dim3(NTRI2 * B_), dim3(1024), 0, stream>>>(Xq, sumsq, aff, colsum, flags);

    kprop<<<dim3(NT, B_), dim3(128), 0, stream>>>(logits, aff, flags, colsum, lf1);
    kprop<<<dim3(NT, B_), dim3(128), 0, stream>>>(lf1, aff, flags, colsum, out);
}

// Round 4
// 357.798 us; speedup vs baseline: 1.4518x; 1.4518x over previous
//
#include <hip/hip_runtime.h>
#include <hip/hip_bf16.h>

#define B_   8
#define C_   1024
#define HW_  4096
#define NK   21
#define NT   32                      // 128-row tiling everywhere
#define NTRI (NT * (NT + 1) / 2)     // 528 upper-triangle 128x128 tiles

using bf16 = __hip_bfloat16;
typedef __attribute__((ext_vector_type(4))) float float4_;
typedef __attribute__((ext_vector_type(8))) int int8v;

#define WAITV0() asm volatile("s_waitcnt vmcnt(0)" ::: "memory")
#define FENCE()  asm volatile("" ::: "memory")
#define BARRIER() do { FENCE(); __builtin_amdgcn_s_barrier(); FENCE(); } while (0)

// ---- kernel 1: transpose + fp8-quantize (UNNORMALIZED) + sumsq reduction ----
__global__ __launch_bounds__(256) void ktrans(const float* __restrict__ x4, float* __restrict__ sumsq,
                                              unsigned char* __restrict__ Xq) {
    int b = blockIdx.z, ct = blockIdx.y, jt = blockIdx.x;
    int c0 = ct * 128, j0 = jt * 64;
    int t = threadIdx.x;
    __shared__ float tile[128][65];   // [c][j]
    __shared__ float ssq[64];

    int jl = t & 63, cl = t >> 6;
    if (t < 64) ssq[t] = 0.f;
    __syncthreads();
    float part = 0.f;
#pragma unroll
    for (int cc = 0; cc < 128; cc += 4) {
        float v = x4[((size_t)b * C_ + c0 + cc + cl) * HW_ + j0 + jl];
        tile[cc + cl][jl] = v;
        part = fmaf(v, v, part);
    }
    atomicAdd(&ssq[jl], part);
    __syncthreads();

    int j = t >> 2, q = t & 3;
    int jg = j0 + j;
    unsigned int pk[8];
#pragma unroll
    for (int g = 0; g < 8; ++g) {
        float f0 = tile[q * 32 + g * 4 + 0][j];
        float f1 = tile[q * 32 + g * 4 + 1][j];
        float f2 = tile[q * 32 + g * 4 + 2][j];
        float f3 = tile[q * 32 + g * 4 + 3][j];
        unsigned int r = 0;
        r = __builtin_amdgcn_cvt_pk_fp8_f32(f0, f1, r, false);
        r = __builtin_amdgcn_cvt_pk_fp8_f32(f2, f3, r, true);
        pk[g] = r;
    }
    unsigned char* dst = Xq + ((size_t)b * HW_ + jg) * C_ + c0 + q * 32;
    *(uint4*)(dst)      = make_uint4(pk[0], pk[1], pk[2], pk[3]);
    *(uint4*)(dst + 16) = make_uint4(pk[4], pk[5], pk[6], pk[7]);

    if (t < 64) atomicAdd(&sumsq[b * HW_ + j0 + t], ssq[t]);
}

// ---- kernel 2: symmetric gram, 128x128 tile, 256 thr = 4 waves (2x2).
// Round-0 geometry (proven no-spill: acc 64 regs, WRITE_SIZE == true output
// footprint) + ONE structural change: double-buffered LDS with 1-tile-ahead
// prefetch (T3 minimum-2-phase). Stage tile t+1 at top of iteration t; one
// vmcnt(0) + one barrier per K-step at the BOTTOM, so the 8 stage loads hide
// under the ~1100-cyc compute phase instead of being drained cold.
// LDS 2x32 KB -> 2 blocks/CU (2 waves/SIMD, reg cap 256 >> ~150 live).
// XCD = blockIdx%8 owns one batch -> its 4 MiB Xq slice == one XCD's L2.
// aff stores nontemporal (write-once; don't evict Xq from L2).
__global__ __launch_bounds__(256, 2) void kgram(const unsigned char* __restrict__ Xq,
                                                const float* __restrict__ sumsq, bf16* __restrict__ aff,
                                                float* __restrict__ colsum, int* __restrict__ flags) {
    int lin = blockIdx.x;
    int b = lin & 7;                 // XCD id == batch id (4224 = 8*528 blocks)
    int p = lin >> 3;
    int it = (int)((2.0f * NT + 1.0f - sqrtf((2.0f * NT + 1.0f) * (2.0f * NT + 1.0f) - 8.0f * (float)p)) * 0.5f);
    while (it > 0 && p < it * NT - it * (it - 1) / 2) --it;
    while (p >= (it + 1) * NT - (it + 1) * it / 2) ++it;
    int jt = it + p - (it * NT - it * (it - 1) / 2);

    int i0 = it * 128, j0 = jt * 128;
    int tid = threadIdx.x, w = tid >> 6, l = tid & 63;
    int wr = w >> 1, wc = w & 1;      // 2x2 wave grid; per-wave output 64x64
    int lrow = l & 15, lk = l >> 4;

    __shared__ __align__(16) unsigned char smem[2][32768];   // each: A 16K | B 16K
    __shared__ int fl;

    const unsigned char* XA = Xq + ((size_t)b * HW_ + i0) * C_;
    const unsigned char* XB = Xq + ((size_t)b * HW_ + j0) * C_;

    int rhi = tid >> 3, sl = tid & 7;      // 32 row-groups x 8 slots

    auto stg = [&](unsigned char* buf, int k0) {
#pragma unroll
        for (int q = 0; q < 4; ++q) {
            int R = q * 32 + rhi;
            int gp = sl ^ (R & 7);         // XOR pre-swizzle of global source
            __builtin_amdgcn_global_load_lds(
                (const __attribute__((address_space(1))) void*)(XA + (size_t)R * C_ + k0 + (gp << 4)),
                (__attribute__((address_space(3))) void*)(buf + R * 128 + (sl << 4)), 16, 0, 0);
            __builtin_amdgcn_global_load_lds(
                (const __attribute__((address_space(1))) void*)(XB + (size_t)R * C_ + k0 + (gp << 4)),
                (__attribute__((address_space(3))) void*)(buf + 16384 + R * 128 + (sl << 4)), 16, 0, 0);
        }
    };

    auto ldfrag = [&](const unsigned char* base, int r) {
        int sw = r & 7;
        uint4 lo = *(const uint4*)(base + r * 128 + (((lk * 2) ^ sw) << 4));
        uint4 hi = *(const uint4*)(base + r * 128 + (((lk * 2 + 1) ^ sw) << 4));
        int8v v; v[0] = lo.x; v[1] = lo.y; v[2] = lo.z; v[3] = lo.w;
        v[4] = hi.x; v[5] = hi.y; v[6] = hi.z; v[7] = hi.w;
        return v;
    };

    float4_ acc[4][4];
#pragma unroll
    for (int m = 0; m < 4; ++m)
#pragma unroll
        for (int n = 0; n < 4; ++n) acc[m][n] = {0.f, 0.f, 0.f, 0.f};

    // prologue: tile 0 -> buf0; drain; sync
    stg(smem[0], 0);
    WAITV0();
    BARRIER();

    for (int kt = 0; kt < 8; ++kt) {
        unsigned char* cur = smem[kt & 1];
        // stage NEXT tile into the other buffer. Safe: previous iteration's
        // trailing barrier guarantees all waves finished reading it.
        if (kt < 7) stg(smem[(kt + 1) & 1], (kt + 1) * 128);

        // compute current tile (compiler manages lgkmcnt for ds_read -> MFMA)
        int8v bv[4];
#pragma unroll
        for (int n = 0; n < 4; ++n) bv[n] = ldfrag(cur + 16384, wc * 64 + n * 16 + lrow);
        __builtin_amdgcn_s_setprio(1);
#pragma unroll
        for (int m = 0; m < 4; ++m) {
            int8v av = ldfrag(cur, wr * 64 + m * 16 + lrow);
#pragma unroll
            for (int n = 0; n < 4; ++n)
                acc[m][n] = __builtin_amdgcn_mfma_scale_f32_16x16x128_f8f6f4(
                    av, bv[n], acc[m][n], 0, 0, 0, 0x7f7f7f7f, 0, 0x7f7f7f7f);
        }
        __builtin_amdgcn_s_setprio(0);

        // drain the prefetch issued at top (it had the whole compute to land)
        if (kt < 7) WAITV0();
        BARRIER();                    // WAR: next iter's stage may overwrite
    }

    // ---- epilogue: deferred normalization rn_i * rn_j ----
    float rnj[4];
#pragma unroll
    for (int n = 0; n < 4; ++n) {
        int j = j0 + wc * 64 + n * 16 + lrow;
        rnj[n] = 1.0f / fmaxf(sqrtf(sumsq[b * HW_ + j]), 1e-12f);
    }
    float rni[4][4];
#pragma unroll
    for (int m = 0; m < 4; ++m)
#pragma unroll
        for (int r = 0; r < 4; ++r) {
            int i = i0 + wr * 64 + m * 16 + lk * 4 + r;
            rni[m][r] = 1.0f / fmaxf(sqrtf(sumsq[b * HW_ + i]), 1e-12f);
        }
    bool any = false;
#pragma unroll
    for (int m = 0; m < 4; ++m)
#pragma unroll
        for (int n = 0; n < 4; ++n)
#pragma unroll
            for (int r = 0; r < 4; ++r) {
                acc[m][n][r] *= rni[m][r] * rnj[n];
                any |= (acc[m][n][r] >= 0.5f);
            }

    if (tid == 0) fl = 0;
    __syncthreads();
    unsigned long long bal = __ballot(any);
    if (l == 0 && bal != 0ull) atomicOr(&fl, 1);
    __syncthreads();
    bool mirror = (it != jt);
    if (tid == 0) {
        flags[(b * NT + it) * NT + jt] = fl;
        if (mirror) flags[(b * NT + jt) * NT + it] = fl;
    }

    if (fl) {
        size_t affb = (size_t)b * HW_ * HW_;
        float rsum[4][4];
#pragma unroll
        for (int m = 0; m < 4; ++m)
#pragma unroll
            for (int r = 0; r < 4; ++r) rsum[m][r] = 0.f;

#pragma unroll
        for (int n = 0; n < 4; ++n) {
            int j = j0 + wc * 64 + n * 16 + lrow;
            float cs = 0.f;
#pragma unroll
            for (int m = 0; m < 4; ++m) {
#pragma unroll
                for (int r = 0; r < 4; ++r) {
                    float v = acc[m][n][r];
                    v = fminf(fmaxf(v, 0.01f), 0.999f);
                    v = (v < 0.5f) ? 0.0f : v;
                    bf16 bb = __float2bfloat16(v);
                    unsigned short us = __builtin_bit_cast(unsigned short, bb);
                    int i = i0 + wr * 64 + m * 16 + lk * 4 + r;
                    __builtin_nontemporal_store(us, (unsigned short*)(aff + affb + (size_t)i * HW_ + j));
                    float bf = __bfloat162float(bb);
                    cs += bf;
                    rsum[m][r] += bf;
                    if (mirror)
                        __builtin_nontemporal_store(us, (unsigned short*)(aff + affb + (size_t)j * HW_ + i));
                }
            }
            cs += __shfl_xor(cs, 16);
            cs += __shfl_xor(cs, 32);
            if (lk == 0) atomicAdd(&colsum[b * HW_ + j], cs);
        }
        if (mirror) {
#pragma unroll
            for (int m = 0; m < 4; ++m) {
#pragma unroll
                for (int r = 0; r < 4; ++r) {
                    float s = rsum[m][r];
                    s += __shfl_xor(s, 1);
                    s += __shfl_xor(s, 2);
                    s += __shfl_xor(s, 4);
                    s += __shfl_xor(s, 8);
                    if (lrow == 0) {
                        int i = i0 + wr * 64 + m * 16 + lk * 4 + r;
                        atomicAdd(&colsum[b * HW_ + i], s);
                    }
                }
            }
        }
    }
}

// ---- kernel 3: out[k][j] = (sum_i lf[k][i]*aff[i][j]) / colsum[j] -----------
__global__ __launch_bounds__(128) void kprop(const float* __restrict__ lf, const bf16* __restrict__ aff,
                                             const int* __restrict__ flags, const float* __restrict__ colsum,
                                             float* __restrict__ outp) {
    int b = blockIdx.y, jt = blockIdx.x;
    int t = threadIdx.x;                 // 128 threads
    int j = jt * 128 + t;
    __shared__ float lfs[NK * 128];
    float acc[NK];
#pragma unroll
    for (int k = 0; k < NK; ++k) acc[k] = 0.f;

    for (int it = 0; it < NT; ++it) {
        if (flags[(b * NT + it) * NT + jt] == 0) continue;   // block-uniform branch
        __syncthreads();
        for (int idx = t; idx < NK * 128; idx += 128)
            lfs[idx] = lf[((size_t)b * NK + (idx >> 7)) * HW_ + it * 128 + (idx & 127)];
        __syncthreads();
        const bf16* ap = aff + ((size_t)b * HW_ + it * 128) * HW_ + j;
        for (int ii = 0; ii < 128; ++ii) {
            float a = __bfloat162float(ap[(size_t)ii * HW_]);
#pragma unroll
            for (int k = 0; k < NK; ++k)
                acc[k] = fmaf(lfs[(k << 7) + ii], a, acc[k]);
        }
    }
    float inv = 1.0f / colsum[b * HW_ + j];
#pragma unroll
    for (int k = 0; k < NK; ++k)
        outp[((size_t)b * NK + k) * HW_ + j] = acc[k] * inv;
}

extern "C" void kernel_launch(void* const* d_in, const int* in_sizes, int n_in,
                              void* d_out, int out_size, void* d_ws, size_t ws_size,
                              hipStream_t stream) {
    const float* x4 = (const float*)d_in[0];
    const float* logits = (const float*)d_in[1];
    float* out = (float*)d_out;

    char* w = (char*)d_ws;
    size_t off = 0;
    auto take = [&](size_t bytes) {
        char* p = w + off;
        off += (bytes + 255) & ~(size_t)255;
        return p;
    };
    unsigned char* Xq = (unsigned char*)take((size_t)B_ * HW_ * C_);    // 32 MiB
    bf16* aff     = (bf16*)take((size_t)B_ * HW_ * HW_ * 2);            // 256 MiB
    float* colsum = (float*)take((size_t)B_ * HW_ * 4);
    int*   flags  = (int*)take((size_t)B_ * NT * NT * 4);
    float* sumsq  = (float*)take((size_t)B_ * HW_ * 4);
    float* lf1    = (float*)take((size_t)B_ * NK * HW_ * 4);

    hipMemsetAsync(colsum, 0,
                   (size_t)B_ * HW_ * 4 + (size_t)B_ * NT * NT * 4 + (size_t)B_ * HW_ * 4, stream);

    ktrans<<<dim3(HW_ / 64, C_ / 128, B_), dim3(256), 0, stream>>>(x4, sumsq, Xq);
    kgram <<<dim3(NTRI * B_), dim3(256), 0, stream>>>(Xq, sumsq, aff, colsum, flags);

    kprop<<<dim3(NT, B_), dim3(128), 0, stream>>>(logits, aff, flags, colsum, lf1);
    kprop<<<dim3(NT, B_), dim3(128), 0, stream>>>(lf1, aff, flags, colsum, out);
}

// Round 5
// 338.094 us; speedup vs baseline: 1.5364x; 1.0583x over previous
//
#include <hip/hip_runtime.h>
#include <hip/hip_bf16.h>

#define B_   8
#define C_   1024
#define HW_  4096
#define NK   21
#define NT   32                      // 128-row tiling everywhere
#define NTRI (NT * (NT + 1) / 2)     // 528 upper-triangle 128x128 tiles

using bf16 = __hip_bfloat16;
typedef __attribute__((ext_vector_type(4))) float float4_;
typedef __attribute__((ext_vector_type(8))) int int8v;

#define WAITV0() asm volatile("s_waitcnt vmcnt(0)" ::: "memory")
#define FENCE()  asm volatile("" ::: "memory")
#define BARRIER() do { FENCE(); __builtin_amdgcn_s_barrier(); FENCE(); } while (0)

// ---- kernel 1: transpose + fp8-quantize (UNNORMALIZED) + sumsq --------------
// Block = 64 j-rows x full C for one batch. The old version wrote Xq as 64
// scattered 16B pieces per wave at 1KB stride (write-sector amplification ->
// ~155us inferred). New: accumulate each j-row's full 1KB of fp8 in LDS, then
// write contiguous 1KB wave-bursts. sumsq: full C per block -> plain store.
__global__ __launch_bounds__(256) void ktrans(const float* __restrict__ x4, float* __restrict__ sumsq,
                                              unsigned char* __restrict__ Xq) {
    int jt = blockIdx.x, b = blockIdx.y;
    int j0 = jt * 64;
    int t = threadIdx.x;
    __shared__ float tin[128][33];            // [c_local][j] transpose chunk
    __shared__ unsigned int outw[32][260];    // [j][c-word] padded (bank spread + 16B align)
    __shared__ float ssq[32];

    int jl = t & 31, cl = t >> 5;             // phase1: 8 c-rows x 32 j
    int qq = t >> 5, jq = t & 31;             // phase2: 8 c-segs x 32 j

    for (int jg = 0; jg < 2; ++jg) {
        int jbase = j0 + jg * 32;
        if (t < 32) ssq[t] = 0.f;
        float part = 0.f;

        for (int ct = 0; ct < 8; ++ct) {
            __syncthreads();                  // protect tin from prev phase2 readers
#pragma unroll
            for (int cc = 0; cc < 16; ++cc) {
                float v = x4[((size_t)b * C_ + ct * 128 + cc * 8 + cl) * HW_ + jbase + jl];
                tin[cc * 8 + cl][jl] = v;
                part = fmaf(v, v, part);
            }
            __syncthreads();
            // quantize 16 c-values -> 4 u32 words into the row buffer
            unsigned int wv[4];
#pragma unroll
            for (int g = 0; g < 4; ++g) {
                float f0 = tin[qq * 16 + g * 4 + 0][jq];
                float f1 = tin[qq * 16 + g * 4 + 1][jq];
                float f2 = tin[qq * 16 + g * 4 + 2][jq];
                float f3 = tin[qq * 16 + g * 4 + 3][jq];
                unsigned int r = 0;
                r = __builtin_amdgcn_cvt_pk_fp8_f32(f0, f1, r, false);
                r = __builtin_amdgcn_cvt_pk_fp8_f32(f2, f3, r, true);
                wv[g] = r;
            }
            *(uint4*)&outw[jq][ct * 32 + qq * 4] = make_uint4(wv[0], wv[1], wv[2], wv[3]);
        }
        atomicAdd(&ssq[jl], part);
        __syncthreads();                      // outw complete + ssq complete

        // phase3: 32 rows x 1KB, fully coalesced (wave = 1024B contiguous)
#pragma unroll
        for (int ps = 0; ps < 8; ++ps) {
            int r = ps * 4 + (t >> 6);
            int ch = t & 63;
            uint4 v = *(const uint4*)&outw[r][ch * 4];
            *(uint4*)(Xq + ((size_t)b * HW_ + jbase + r) * C_ + ch * 16) = v;
        }
        if (t < 32) sumsq[b * HW_ + jbase + t] = ssq[t];
        __syncthreads();                      // protect outw/ssq for next jg
    }
}

// ---- kernel 2: symmetric gram, 128x128 tile, 256 thr = 4 waves (2x2) --------
// UNCHANGED from round 4 (106us, no spill, FETCH==compulsory) except: aff
// stores revert to plain (write-allocate) so kprop's column walk hits L2/L3
// instead of HBM. Counter note: SQ_LDS_BANK_CONFLICT = 2048/block = 8 per
// global_load_lds wave-burst = inherent 1KB serialization (phantom); reads
// are conflict-free.
__global__ __launch_bounds__(256, 2) void kgram(const unsigned char* __restrict__ Xq,
                                                const float* __restrict__ sumsq, bf16* __restrict__ aff,
                                                float* __restrict__ colsum, int* __restrict__ flags) {
    int lin = blockIdx.x;
    int b = lin & 7;                 // XCD id == batch id (4224 = 8*528 blocks)
    int p = lin >> 3;
    int it = (int)((2.0f * NT + 1.0f - sqrtf((2.0f * NT + 1.0f) * (2.0f * NT + 1.0f) - 8.0f * (float)p)) * 0.5f);
    while (it > 0 && p < it * NT - it * (it - 1) / 2) --it;
    while (p >= (it + 1) * NT - (it + 1) * it / 2) ++it;
    int jt = it + p - (it * NT - it * (it - 1) / 2);

    int i0 = it * 128, j0 = jt * 128;
    int tid = threadIdx.x, w = tid >> 6, l = tid & 63;
    int wr = w >> 1, wc = w & 1;      // 2x2 wave grid; per-wave output 64x64
    int lrow = l & 15, lk = l >> 4;

    __shared__ __align__(16) unsigned char smem[2][32768];   // each: A 16K | B 16K
    __shared__ int fl;

    const unsigned char* XA = Xq + ((size_t)b * HW_ + i0) * C_;
    const unsigned char* XB = Xq + ((size_t)b * HW_ + j0) * C_;

    int rhi = tid >> 3, sl = tid & 7;      // 32 row-groups x 8 slots

    auto stg = [&](unsigned char* buf, int k0) {
#pragma unroll
        for (int q = 0; q < 4; ++q) {
            int R = q * 32 + rhi;
            int gp = sl ^ (R & 7);         // XOR pre-swizzle of global source
            __builtin_amdgcn_global_load_lds(
                (const __attribute__((address_space(1))) void*)(XA + (size_t)R * C_ + k0 + (gp << 4)),
                (__attribute__((address_space(3))) void*)(buf + R * 128 + (sl << 4)), 16, 0, 0);
            __builtin_amdgcn_global_load_lds(
                (const __attribute__((address_space(1))) void*)(XB + (size_t)R * C_ + k0 + (gp << 4)),
                (__attribute__((address_space(3))) void*)(buf + 16384 + R * 128 + (sl << 4)), 16, 0, 0);
        }
    };

    auto ldfrag = [&](const unsigned char* base, int r) {
        int sw = r & 7;
        uint4 lo = *(const uint4*)(base + r * 128 + (((lk * 2) ^ sw) << 4));
        uint4 hi = *(const uint4*)(base + r * 128 + (((lk * 2 + 1) ^ sw) << 4));
        int8v v; v[0] = lo.x; v[1] = lo.y; v[2] = lo.z; v[3] = lo.w;
        v[4] = hi.x; v[5] = hi.y; v[6] = hi.z; v[7] = hi.w;
        return v;
    };

    float4_ acc[4][4];
#pragma unroll
    for (int m = 0; m < 4; ++m)
#pragma unroll
        for (int n = 0; n < 4; ++n) acc[m][n] = {0.f, 0.f, 0.f, 0.f};

    // prologue: tile 0 -> buf0; drain; sync
    stg(smem[0], 0);
    WAITV0();
    BARRIER();

    for (int kt = 0; kt < 8; ++kt) {
        unsigned char* cur = smem[kt & 1];
        if (kt < 7) stg(smem[(kt + 1) & 1], (kt + 1) * 128);

        int8v bv[4];
#pragma unroll
        for (int n = 0; n < 4; ++n) bv[n] = ldfrag(cur + 16384, wc * 64 + n * 16 + lrow);
        __builtin_amdgcn_s_setprio(1);
#pragma unroll
        for (int m = 0; m < 4; ++m) {
            int8v av = ldfrag(cur, wr * 64 + m * 16 + lrow);
#pragma unroll
            for (int n = 0; n < 4; ++n)
                acc[m][n] = __builtin_amdgcn_mfma_scale_f32_16x16x128_f8f6f4(
                    av, bv[n], acc[m][n], 0, 0, 0, 0x7f7f7f7f, 0, 0x7f7f7f7f);
        }
        __builtin_amdgcn_s_setprio(0);

        if (kt < 7) WAITV0();
        BARRIER();
    }

    // ---- epilogue: deferred normalization rn_i * rn_j ----
    float rnj[4];
#pragma unroll
    for (int n = 0; n < 4; ++n) {
        int j = j0 + wc * 64 + n * 16 + lrow;
        rnj[n] = 1.0f / fmaxf(sqrtf(sumsq[b * HW_ + j]), 1e-12f);
    }
    float rni[4][4];
#pragma unroll
    for (int m = 0; m < 4; ++m)
#pragma unroll
        for (int r = 0; r < 4; ++r) {
            int i = i0 + wr * 64 + m * 16 + lk * 4 + r;
            rni[m][r] = 1.0f / fmaxf(sqrtf(sumsq[b * HW_ + i]), 1e-12f);
        }
    bool any = false;
#pragma unroll
    for (int m = 0; m < 4; ++m)
#pragma unroll
        for (int n = 0; n < 4; ++n)
#pragma unroll
            for (int r = 0; r < 4; ++r) {
                acc[m][n][r] *= rni[m][r] * rnj[n];
                any |= (acc[m][n][r] >= 0.5f);
            }

    if (tid == 0) fl = 0;
    __syncthreads();
    unsigned long long bal = __ballot(any);
    if (l == 0 && bal != 0ull) atomicOr(&fl, 1);
    __syncthreads();
    bool mirror = (it != jt);
    if (tid == 0) {
        flags[(b * NT + it) * NT + jt] = fl;
        if (mirror) flags[(b * NT + jt) * NT + it] = fl;
    }

    if (fl) {
        size_t affb = (size_t)b * HW_ * HW_;
        float rsum[4][4];
#pragma unroll
        for (int m = 0; m < 4; ++m)
#pragma unroll
            for (int r = 0; r < 4; ++r) rsum[m][r] = 0.f;

#pragma unroll
        for (int n = 0; n < 4; ++n) {
            int j = j0 + wc * 64 + n * 16 + lrow;
            float cs = 0.f;
#pragma unroll
            for (int m = 0; m < 4; ++m) {
#pragma unroll
                for (int r = 0; r < 4; ++r) {
                    float v = acc[m][n][r];
                    v = fminf(fmaxf(v, 0.01f), 0.999f);
                    v = (v < 0.5f) ? 0.0f : v;
                    bf16 bb = __float2bfloat16(v);
                    int i = i0 + wr * 64 + m * 16 + lk * 4 + r;
                    aff[affb + (size_t)i * HW_ + j] = bb;
                    float bf = __bfloat162float(bb);
                    cs += bf;
                    rsum[m][r] += bf;
                    if (mirror) aff[affb + (size_t)j * HW_ + i] = bb;
                }
            }
            cs += __shfl_xor(cs, 16);
            cs += __shfl_xor(cs, 32);
            if (lk == 0) atomicAdd(&colsum[b * HW_ + j], cs);
        }
        if (mirror) {
#pragma unroll
            for (int m = 0; m < 4; ++m) {
#pragma unroll
                for (int r = 0; r < 4; ++r) {
                    float s = rsum[m][r];
                    s += __shfl_xor(s, 1);
                    s += __shfl_xor(s, 2);
                    s += __shfl_xor(s, 4);
                    s += __shfl_xor(s, 8);
                    if (lrow == 0) {
                        int i = i0 + wr * 64 + m * 16 + lk * 4 + r;
                        atomicAdd(&colsum[b * HW_ + i], s);
                    }
                }
            }
        }
    }
}

// ---- kernel 3: out[k][j] = (sum_i lf[k][i]*aff[i][j]) / colsum[j] -----------
// Latency fix: old version = 1 block of 2 waves per CU walking a 128-step
// dependent bf16 column chain (~500cyc/step). New: 64-col blocks, 4 waves
// split the ii-range 4 ways, 4x unrolled independent loads, LDS combine.
__global__ __launch_bounds__(256) void kprop(const float* __restrict__ lf, const bf16* __restrict__ aff,
                                             const int* __restrict__ flags, const float* __restrict__ colsum,
                                             float* __restrict__ outp) {
    int jt = blockIdx.x, b = blockIdx.y;       // 64 tiles of 64 cols
    int t = threadIdx.x;
    int q = t >> 6, jl = t & 63;
    int j = jt * 64 + jl;
    __shared__ float lfs[NK * 128];
    __shared__ float ps[3][NK][64];
    float acc[NK];
#pragma unroll
    for (int k = 0; k < NK; ++k) acc[k] = 0.f;

    for (int it = 0; it < NT; ++it) {
        if (flags[(b * NT + it) * NT + (jt >> 1)] == 0) continue;   // block-uniform
        __syncthreads();
        for (int idx = t; idx < NK * 128; idx += 256)
            lfs[idx] = lf[((size_t)b * NK + (idx >> 7)) * HW_ + it * 128 + (idx & 127)];
        __syncthreads();
        const bf16* ap = aff + ((size_t)b * HW_ + it * 128 + q * 32) * HW_ + j;
        for (int ii = 0; ii < 32; ii += 4) {
            float a0 = __bfloat162float(ap[(size_t)(ii + 0) * HW_]);
            float a1 = __bfloat162float(ap[(size_t)(ii + 1) * HW_]);
            float a2 = __bfloat162float(ap[(size_t)(ii + 2) * HW_]);
            float a3 = __bfloat162float(ap[(size_t)(ii + 3) * HW_]);
            int base = (q * 32 + ii);
#pragma unroll
            for (int k = 0; k < NK; ++k)
                acc[k] = fmaf(lfs[(k << 7) + base + 0], a0,
                          fmaf(lfs[(k << 7) + base + 1], a1,
                          fmaf(lfs[(k << 7) + base + 2], a2,
                          fmaf(lfs[(k << 7) + base + 3], a3, acc[k]))));
        }
    }

    if (q) {
#pragma unroll
        for (int k = 0; k < NK; ++k) ps[q - 1][k][jl] = acc[k];
    }
    __syncthreads();
    if (q == 0) {
        float inv = 1.0f / colsum[b * HW_ + j];
#pragma unroll
        for (int k = 0; k < NK; ++k) {
            float s = acc[k] + ps[0][k][jl] + ps[1][k][jl] + ps[2][k][jl];
            outp[((size_t)b * NK + k) * HW_ + j] = s * inv;
        }
    }
}

extern "C" void kernel_launch(void* const* d_in, const int* in_sizes, int n_in,
                              void* d_out, int out_size, void* d_ws, size_t ws_size,
                              hipStream_t stream) {
    const float* x4 = (const float*)d_in[0];
    const float* logits = (const float*)d_in[1];
    float* out = (float*)d_out;

    char* w = (char*)d_ws;
    size_t off = 0;
    auto take = [&](size_t bytes) {
        char* p = w + off;
        off += (bytes + 255) & ~(size_t)255;
        return p;
    };
    unsigned char* Xq = (unsigned char*)take((size_t)B_ * HW_ * C_);    // 32 MiB
    bf16* aff     = (bf16*)take((size_t)B_ * HW_ * HW_ * 2);            // 256 MiB
    float* colsum = (float*)take((size_t)B_ * HW_ * 4);
    int*   flags  = (int*)take((size_t)B_ * NT * NT * 4);
    float* sumsq  = (float*)take((size_t)B_ * HW_ * 4);
    float* lf1    = (float*)take((size_t)B_ * NK * HW_ * 4);

    hipMemsetAsync(colsum, 0,
                   (size_t)B_ * HW_ * 4 + (size_t)B_ * NT * NT * 4, stream);

    ktrans<<<dim3(64, B_), dim3(256), 0, stream>>>(x4, sumsq, Xq);
    kgram <<<dim3(NTRI * B_), dim3(256), 0, stream>>>(Xq, sumsq, aff, colsum, flags);

    kprop<<<dim3(64, B_), dim3(256), 0, stream>>>(logits, aff, flags, colsum, lf1);
    kprop<<<dim3(64, B_), dim3(256), 0, stream>>>(lf1, aff, flags, colsum, out);
}

// Round 6
// 336.508 us; speedup vs baseline: 1.5436x; 1.0047x over previous
//
#include <hip/hip_runtime.h>
#include <hip/hip_bf16.h>

#define B_   8
#define C_   1024
#define HW_  4096
#define NK   21
#define NT   32                      // 128-row tiling everywhere
#define NTRI (NT * (NT + 1) / 2)     // 528 upper-triangle 128x128 tiles

using bf16 = __hip_bfloat16;
typedef __attribute__((ext_vector_type(4))) float float4_;
typedef __attribute__((ext_vector_type(8))) int int8v;

#define WAITV0() asm volatile("s_waitcnt vmcnt(0)" ::: "memory")
#define FENCE()  asm volatile("" ::: "memory")
#define BARRIER() do { FENCE(); __builtin_amdgcn_s_barrier(); FENCE(); } while (0)

// ---- kernel 1: transpose + fp8-quantize (UNNORMALIZED) + sumsq --------------
// Also zeroes this block's colsum slice (replaces the hipMemsetAsync launch;
// kernel-boundary ordering guarantees it lands before kgram's atomics).
// flags need no zeroing: kgram writes every (it,jt) unconditionally.
__global__ __launch_bounds__(256) void ktrans(const float* __restrict__ x4, float* __restrict__ sumsq,
                                              unsigned char* __restrict__ Xq, float* __restrict__ colsum) {
    int jt = blockIdx.x, b = blockIdx.y;
    int j0 = jt * 64;
    int t = threadIdx.x;
    __shared__ float tin[128][33];            // [c_local][j] transpose chunk
    __shared__ unsigned int outw[32][260];    // [j][c-word] padded (bank spread + 16B align)
    __shared__ float ssq[32];

    if (t < 64) colsum[b * HW_ + j0 + t] = 0.f;

    int jl = t & 31, cl = t >> 5;             // phase1: 8 c-rows x 32 j
    int qq = t >> 5, jq = t & 31;             // phase2: 8 c-segs x 32 j

    for (int jg = 0; jg < 2; ++jg) {
        int jbase = j0 + jg * 32;
        if (t < 32) ssq[t] = 0.f;
        float part = 0.f;

        for (int ct = 0; ct < 8; ++ct) {
            __syncthreads();                  // protect tin from prev phase2 readers
#pragma unroll
            for (int cc = 0; cc < 16; ++cc) {
                float v = x4[((size_t)b * C_ + ct * 128 + cc * 8 + cl) * HW_ + jbase + jl];
                tin[cc * 8 + cl][jl] = v;
                part = fmaf(v, v, part);
            }
            __syncthreads();
            // quantize 16 c-values -> 4 u32 words into the row buffer
            unsigned int wv[4];
#pragma unroll
            for (int g = 0; g < 4; ++g) {
                float f0 = tin[qq * 16 + g * 4 + 0][jq];
                float f1 = tin[qq * 16 + g * 4 + 1][jq];
                float f2 = tin[qq * 16 + g * 4 + 2][jq];
                float f3 = tin[qq * 16 + g * 4 + 3][jq];
                unsigned int r = 0;
                r = __builtin_amdgcn_cvt_pk_fp8_f32(f0, f1, r, false);
                r = __builtin_amdgcn_cvt_pk_fp8_f32(f2, f3, r, true);
                wv[g] = r;
            }
            *(uint4*)&outw[jq][ct * 32 + qq * 4] = make_uint4(wv[0], wv[1], wv[2], wv[3]);
        }
        atomicAdd(&ssq[jl], part);
        __syncthreads();                      // outw complete + ssq complete

        // phase3: 32 rows x 1KB, fully coalesced (wave = 1024B contiguous)
#pragma unroll
        for (int ps = 0; ps < 8; ++ps) {
            int r = ps * 4 + (t >> 6);
            int ch = t & 63;
            uint4 v = *(const uint4*)&outw[r][ch * 4];
            *(uint4*)(Xq + ((size_t)b * HW_ + jbase + r) * C_ + ch * 16) = v;
        }
        if (t < 32) sumsq[b * HW_ + jbase + t] = ssq[t];
        __syncthreads();                      // protect outw/ssq for next jg
    }
}

// ---- kernel 2: symmetric gram, 128x128 tile, 256 thr = 4 waves (2x2) --------
// FROZEN from round 5 (106us, 1.34 PF = 82% of the m148 MX-fp8 reference for
// this 2-barrier structure; no spill, FETCH == compulsory).
__global__ __launch_bounds__(256, 2) void kgram(const unsigned char* __restrict__ Xq,
                                                const float* __restrict__ sumsq, bf16* __restrict__ aff,
                                                float* __restrict__ colsum, int* __restrict__ flags) {
    int lin = blockIdx.x;
    int b = lin & 7;                 // XCD id == batch id (4224 = 8*528 blocks)
    int p = lin >> 3;
    int it = (int)((2.0f * NT + 1.0f - sqrtf((2.0f * NT + 1.0f) * (2.0f * NT + 1.0f) - 8.0f * (float)p)) * 0.5f);
    while (it > 0 && p < it * NT - it * (it - 1) / 2) --it;
    while (p >= (it + 1) * NT - (it + 1) * it / 2) ++it;
    int jt = it + p - (it * NT - it * (it - 1) / 2);

    int i0 = it * 128, j0 = jt * 128;
    int tid = threadIdx.x, w = tid >> 6, l = tid & 63;
    int wr = w >> 1, wc = w & 1;      // 2x2 wave grid; per-wave output 64x64
    int lrow = l & 15, lk = l >> 4;

    __shared__ __align__(16) unsigned char smem[2][32768];   // each: A 16K | B 16K
    __shared__ int fl;

    const unsigned char* XA = Xq + ((size_t)b * HW_ + i0) * C_;
    const unsigned char* XB = Xq + ((size_t)b * HW_ + j0) * C_;

    int rhi = tid >> 3, sl = tid & 7;      // 32 row-groups x 8 slots

    auto stg = [&](unsigned char* buf, int k0) {
#pragma unroll
        for (int q = 0; q < 4; ++q) {
            int R = q * 32 + rhi;
            int gp = sl ^ (R & 7);         // XOR pre-swizzle of global source
            __builtin_amdgcn_global_load_lds(
                (const __attribute__((address_space(1))) void*)(XA + (size_t)R * C_ + k0 + (gp << 4)),
                (__attribute__((address_space(3))) void*)(buf + R * 128 + (sl << 4)), 16, 0, 0);
            __builtin_amdgcn_global_load_lds(
                (const __attribute__((address_space(1))) void*)(XB + (size_t)R * C_ + k0 + (gp << 4)),
                (__attribute__((address_space(3))) void*)(buf + 16384 + R * 128 + (sl << 4)), 16, 0, 0);
        }
    };

    auto ldfrag = [&](const unsigned char* base, int r) {
        int sw = r & 7;
        uint4 lo = *(const uint4*)(base + r * 128 + (((lk * 2) ^ sw) << 4));
        uint4 hi = *(const uint4*)(base + r * 128 + (((lk * 2 + 1) ^ sw) << 4));
        int8v v; v[0] = lo.x; v[1] = lo.y; v[2] = lo.z; v[3] = lo.w;
        v[4] = hi.x; v[5] = hi.y; v[6] = hi.z; v[7] = hi.w;
        return v;
    };

    float4_ acc[4][4];
#pragma unroll
    for (int m = 0; m < 4; ++m)
#pragma unroll
        for (int n = 0; n < 4; ++n) acc[m][n] = {0.f, 0.f, 0.f, 0.f};

    // prologue: tile 0 -> buf0; drain; sync
    stg(smem[0], 0);
    WAITV0();
    BARRIER();

    for (int kt = 0; kt < 8; ++kt) {
        unsigned char* cur = smem[kt & 1];
        if (kt < 7) stg(smem[(kt + 1) & 1], (kt + 1) * 128);

        int8v bv[4];
#pragma unroll
        for (int n = 0; n < 4; ++n) bv[n] = ldfrag(cur + 16384, wc * 64 + n * 16 + lrow);
        __builtin_amdgcn_s_setprio(1);
#pragma unroll
        for (int m = 0; m < 4; ++m) {
            int8v av = ldfrag(cur, wr * 64 + m * 16 + lrow);
#pragma unroll
            for (int n = 0; n < 4; ++n)
                acc[m][n] = __builtin_amdgcn_mfma_scale_f32_16x16x128_f8f6f4(
                    av, bv[n], acc[m][n], 0, 0, 0, 0x7f7f7f7f, 0, 0x7f7f7f7f);
        }
        __builtin_amdgcn_s_setprio(0);

        if (kt < 7) WAITV0();
        BARRIER();
    }

    // ---- epilogue: deferred normalization rn_i * rn_j ----
    float rnj[4];
#pragma unroll
    for (int n = 0; n < 4; ++n) {
        int j = j0 + wc * 64 + n * 16 + lrow;
        rnj[n] = 1.0f / fmaxf(sqrtf(sumsq[b * HW_ + j]), 1e-12f);
    }
    float rni[4][4];
#pragma unroll
    for (int m = 0; m < 4; ++m)
#pragma unroll
        for (int r = 0; r < 4; ++r) {
            int i = i0 + wr * 64 + m * 16 + lk * 4 + r;
            rni[m][r] = 1.0f / fmaxf(sqrtf(sumsq[b * HW_ + i]), 1e-12f);
        }
    bool any = false;
#pragma unroll
    for (int m = 0; m < 4; ++m)
#pragma unroll
        for (int n = 0; n < 4; ++n)
#pragma unroll
            for (int r = 0; r < 4; ++r) {
                acc[m][n][r] *= rni[m][r] * rnj[n];
                any |= (acc[m][n][r] >= 0.5f);
            }

    if (tid == 0) fl = 0;
    __syncthreads();
    unsigned long long bal = __ballot(any);
    if (l == 0 && bal != 0ull) atomicOr(&fl, 1);
    __syncthreads();
    bool mirror = (it != jt);
    if (tid == 0) {
        flags[(b * NT + it) * NT + jt] = fl;
        if (mirror) flags[(b * NT + jt) * NT + it] = fl;
    }

    if (fl) {
        size_t affb = (size_t)b * HW_ * HW_;
        float rsum[4][4];
#pragma unroll
        for (int m = 0; m < 4; ++m)
#pragma unroll
            for (int r = 0; r < 4; ++r) rsum[m][r] = 0.f;

#pragma unroll
        for (int n = 0; n < 4; ++n) {
            int j = j0 + wc * 64 + n * 16 + lrow;
            float cs = 0.f;
#pragma unroll
            for (int m = 0; m < 4; ++m) {
#pragma unroll
                for (int r = 0; r < 4; ++r) {
                    float v = acc[m][n][r];
                    v = fminf(fmaxf(v, 0.01f), 0.999f);
                    v = (v < 0.5f) ? 0.0f : v;
                    bf16 bb = __float2bfloat16(v);
                    int i = i0 + wr * 64 + m * 16 + lk * 4 + r;
                    aff[affb + (size_t)i * HW_ + j] = bb;
                    float bf = __bfloat162float(bb);
                    cs += bf;
                    rsum[m][r] += bf;
                    if (mirror) aff[affb + (size_t)j * HW_ + i] = bb;
                }
            }
            cs += __shfl_xor(cs, 16);
            cs += __shfl_xor(cs, 32);
            if (lk == 0) atomicAdd(&colsum[b * HW_ + j], cs);
        }
        if (mirror) {
#pragma unroll
            for (int m = 0; m < 4; ++m) {
#pragma unroll
                for (int r = 0; r < 4; ++r) {
                    float s = rsum[m][r];
                    s += __shfl_xor(s, 1);
                    s += __shfl_xor(s, 2);
                    s += __shfl_xor(s, 4);
                    s += __shfl_xor(s, 8);
                    if (lrow == 0) {
                        int i = i0 + wr * 64 + m * 16 + lk * 4 + r;
                        atomicAdd(&colsum[b * HW_ + i], s);
                    }
                }
            }
        }
    }
}

// ---- kernel 3: BOTH propagation rounds fused (pcm = 2), no grid sync -------
// out[k][j] = (sum_i lf1[k][i] a[i][j]) / cs[j], lf1[k][i] = (sum_h lf[k][h]
// a[h][i]) / cs[i]. Each j-tile block recomputes the lf1 i-tiles it needs
// (only flagged i-tiles; each needs only flagged h-tiles -> for sparse flags
// this is ~2x one propagation's work, and always correct for dense flags).
// Removes one kernel launch + the lf1 global round-trip.
__global__ __launch_bounds__(256) void kprop2(const float* __restrict__ lf, const bf16* __restrict__ aff,
                                              const int* __restrict__ flags, const float* __restrict__ colsum,
                                              float* __restrict__ outp) {
    int jt = blockIdx.x, b = blockIdx.y;       // 32 tiles of 128 cols
    int t = threadIdx.x;
    int q = t >> 7, jl = t & 127;              // 2-way row-range split
    int j = jt * 128 + jl;
    __shared__ float lfs[NK * 128];            // staged lf rows / q=1 partials
    __shared__ float lf1t[NK * 128];           // recomputed lf1 i-tile (f32)

    float oacc[NK];
#pragma unroll
    for (int k = 0; k < NK; ++k) oacc[k] = 0.f;

    for (int it = 0; it < NT; ++it) {
        if (flags[(b * NT + it) * NT + jt] == 0) continue;   // block-uniform

        // ---- pass 1: build lf1 for i-tile 'it' ----
        float racc[NK];
#pragma unroll
        for (int k = 0; k < NK; ++k) racc[k] = 0.f;

        for (int ht = 0; ht < NT; ++ht) {
            if (flags[(b * NT + ht) * NT + it] == 0) continue;   // block-uniform
            __syncthreads();                   // protect lfs from prev readers
            for (int idx = t; idx < NK * 128; idx += 256)
                lfs[idx] = lf[((size_t)b * NK + (idx >> 7)) * HW_ + ht * 128 + (idx & 127)];
            __syncthreads();
            const bf16* ap = aff + ((size_t)b * HW_ + ht * 128 + q * 64) * HW_ + it * 128 + jl;
            for (int ii = 0; ii < 64; ii += 4) {
                float a0 = __bfloat162float(ap[(size_t)(ii + 0) * HW_]);
                float a1 = __bfloat162float(ap[(size_t)(ii + 1) * HW_]);
                float a2 = __bfloat162float(ap[(size_t)(ii + 2) * HW_]);
                float a3 = __bfloat162float(ap[(size_t)(ii + 3) * HW_]);
                int base = q * 64 + ii;
#pragma unroll
                for (int k = 0; k < NK; ++k)
                    racc[k] = fmaf(lfs[(k << 7) + base + 0], a0,
                               fmaf(lfs[(k << 7) + base + 1], a1,
                               fmaf(lfs[(k << 7) + base + 2], a2,
                               fmaf(lfs[(k << 7) + base + 3], a3, racc[k]))));
            }
        }
        // combine q halves + normalize by colsum over i-columns
        __syncthreads();                       // lfs free; prev lf1t readers done
        if (q == 1) {
#pragma unroll
            for (int k = 0; k < NK; ++k) lfs[(k << 7) + jl] = racc[k];
        }
        __syncthreads();
        if (q == 0) {
            float invi = 1.0f / colsum[b * HW_ + it * 128 + jl];
#pragma unroll
            for (int k = 0; k < NK; ++k)
                lf1t[(k << 7) + jl] = (racc[k] + lfs[(k << 7) + jl]) * invi;
        }
        __syncthreads();

        // ---- pass 2: out += lf1t * aff[it -> jt] ----
        const bf16* ap2 = aff + ((size_t)b * HW_ + it * 128 + q * 64) * HW_ + j;
        for (int ii = 0; ii < 64; ii += 4) {
            float a0 = __bfloat162float(ap2[(size_t)(ii + 0) * HW_]);
            float a1 = __bfloat162float(ap2[(size_t)(ii + 1) * HW_]);
            float a2 = __bfloat162float(ap2[(size_t)(ii + 2) * HW_]);
            float a3 = __bfloat162float(ap2[(size_t)(ii + 3) * HW_]);
            int base = q * 64 + ii;
#pragma unroll
            for (int k = 0; k < NK; ++k)
                oacc[k] = fmaf(lf1t[(k << 7) + base + 0], a0,
                           fmaf(lf1t[(k << 7) + base + 1], a1,
                           fmaf(lf1t[(k << 7) + base + 2], a2,
                           fmaf(lf1t[(k << 7) + base + 3], a3, oacc[k]))));
        }
    }

    // epilogue: combine q halves, divide by colsum[j]
    __syncthreads();
    if (q == 1) {
#pragma unroll
        for (int k = 0; k < NK; ++k) lfs[(k << 7) + jl] = oacc[k];
    }
    __syncthreads();
    if (q == 0) {
        float inv = 1.0f / colsum[b * HW_ + j];
#pragma unroll
        for (int k = 0; k < NK; ++k)
            outp[((size_t)b * NK + k) * HW_ + j] = (oacc[k] + lfs[(k << 7) + jl]) * inv;
    }
}

extern "C" void kernel_launch(void* const* d_in, const int* in_sizes, int n_in,
                              void* d_out, int out_size, void* d_ws, size_t ws_size,
                              hipStream_t stream) {
    const float* x4 = (const float*)d_in[0];
    const float* logits = (const float*)d_in[1];
    float* out = (float*)d_out;

    char* w = (char*)d_ws;
    size_t off = 0;
    auto take = [&](size_t bytes) {
        char* p = w + off;
        off += (bytes + 255) & ~(size_t)255;
        return p;
    };
    unsigned char* Xq = (unsigned char*)take((size_t)B_ * HW_ * C_);    // 32 MiB
    bf16* aff     = (bf16*)take((size_t)B_ * HW_ * HW_ * 2);            // 256 MiB
    float* colsum = (float*)take((size_t)B_ * HW_ * 4);
    int*   flags  = (int*)take((size_t)B_ * NT * NT * 4);
    float* sumsq  = (float*)take((size_t)B_ * HW_ * 4);

    // 3 launches total: ktrans zeroes colsum; kgram writes flags densely.
    ktrans<<<dim3(64, B_), dim3(256), 0, stream>>>(x4, sumsq, Xq, colsum);
    kgram <<<dim3(NTRI * B_), dim3(256), 0, stream>>>(Xq, sumsq, aff, colsum, flags);
    kprop2<<<dim3(NT, B_), dim3(256), 0, stream>>>(logits, aff, flags, colsum, out);
}

// Round 7
// 329.809 us; speedup vs baseline: 1.5750x; 1.0203x over previous
//
#include <hip/hip_runtime.h>
#include <hip/hip_bf16.h>

#define B_   8
#define C_   1024
#define HW_  4096
#define NK   21
#define NT   32                      // 128-row tiling everywhere
#define NTRI (NT * (NT + 1) / 2)     // 528 upper-triangle 128x128 tiles

using bf16 = __hip_bfloat16;
typedef __attribute__((ext_vector_type(16))) float f32x16;
typedef __attribute__((ext_vector_type(8))) int int8v;

#define WAITV0() asm volatile("s_waitcnt vmcnt(0)" ::: "memory")
#define FENCE()  asm volatile("" ::: "memory")
#define BARRIER() do { FENCE(); __builtin_amdgcn_s_barrier(); FENCE(); } while (0)

// ---- kernel 1: transpose + fp8-quantize (UNNORMALIZED) + inv-norm ----------
// Stores rn[j] = 1/max(sqrt(sumsq),eps) directly (moves the sqrt out of
// kgram's epilogue). Also zeroes this block's colsum slice.
__global__ __launch_bounds__(256) void ktrans(const float* __restrict__ x4, float* __restrict__ rn,
                                              unsigned char* __restrict__ Xq, float* __restrict__ colsum) {
    int jt = blockIdx.x, b = blockIdx.y;
    int j0 = jt * 64;
    int t = threadIdx.x;
    __shared__ float tin[128][33];            // [c_local][j] transpose chunk
    __shared__ unsigned int outw[32][260];    // [j][c-word] padded (bank spread + 16B align)
    __shared__ float ssq[32];

    if (t < 64) colsum[b * HW_ + j0 + t] = 0.f;

    int jl = t & 31, cl = t >> 5;             // phase1: 8 c-rows x 32 j
    int qq = t >> 5, jq = t & 31;             // phase2: 8 c-segs x 32 j

    for (int jg = 0; jg < 2; ++jg) {
        int jbase = j0 + jg * 32;
        if (t < 32) ssq[t] = 0.f;
        float part = 0.f;

        for (int ct = 0; ct < 8; ++ct) {
            __syncthreads();                  // protect tin from prev phase2 readers
#pragma unroll
            for (int cc = 0; cc < 16; ++cc) {
                float v = x4[((size_t)b * C_ + ct * 128 + cc * 8 + cl) * HW_ + jbase + jl];
                tin[cc * 8 + cl][jl] = v;
                part = fmaf(v, v, part);
            }
            __syncthreads();
            unsigned int wv[4];
#pragma unroll
            for (int g = 0; g < 4; ++g) {
                float f0 = tin[qq * 16 + g * 4 + 0][jq];
                float f1 = tin[qq * 16 + g * 4 + 1][jq];
                float f2 = tin[qq * 16 + g * 4 + 2][jq];
                float f3 = tin[qq * 16 + g * 4 + 3][jq];
                unsigned int r = 0;
                r = __builtin_amdgcn_cvt_pk_fp8_f32(f0, f1, r, false);
                r = __builtin_amdgcn_cvt_pk_fp8_f32(f2, f3, r, true);
                wv[g] = r;
            }
            *(uint4*)&outw[jq][ct * 32 + qq * 4] = make_uint4(wv[0], wv[1], wv[2], wv[3]);
        }
        atomicAdd(&ssq[jl], part);
        __syncthreads();                      // outw complete + ssq complete

#pragma unroll
        for (int ps = 0; ps < 8; ++ps) {
            int r = ps * 4 + (t >> 6);
            int ch = t & 63;
            uint4 v = *(const uint4*)&outw[r][ch * 4];
            *(uint4*)(Xq + ((size_t)b * HW_ + jbase + r) * C_ + ch * 16) = v;
        }
        if (t < 32) rn[b * HW_ + jbase + t] = 1.0f / fmaxf(sqrtf(ssq[t]), 1e-12f);
        __syncthreads();                      // protect outw/ssq for next jg
    }
}

// ---- kernel 2: symmetric gram, 128x128 tile, 256 thr = 4 waves (2x2) --------
// BK=64 + mfma_scale_f32_32x32x64_f8f6f4: halves the LDS footprint
// (2 x 16 KB dbuf = 33 KB) -> 4 blocks/CU, 4 waves/SIMD (vs 2). Round-6
// analysis: at 106us the LDS pipe was only ~50% busy, MFMA 28% -- the kernel
// is latency/barrier-stalled at low occupancy; doubling co-resident blocks
// lets other blocks' compute cover each block's vmcnt/barrier drain.
// LDS rows are 64 B; swizzle slot^=(row>>1)&3 spreads a 32-row column read
// across all 32 banks (8 passes / 1 KB = b128 minimum, conflict-free).
// Operand layout (32x32): A/B row = lane&31, k-group = lane>>5 (analog of the
// verified 16x16 mapping); C: col=lane&31, row=(reg&3)+4*(lane>>5)+8*(reg>>2).
__global__ __launch_bounds__(256, 4) void kgram(const unsigned char* __restrict__ Xq,
                                                const float* __restrict__ rn, bf16* __restrict__ aff,
                                                float* __restrict__ colsum, int* __restrict__ flags) {
    int lin = blockIdx.x;
    int b = lin & 7;                 // XCD id == batch id (4224 = 8*528 blocks)
    int p = lin >> 3;
    int it = (int)((2.0f * NT + 1.0f - sqrtf((2.0f * NT + 1.0f) * (2.0f * NT + 1.0f) - 8.0f * (float)p)) * 0.5f);
    while (it > 0 && p < it * NT - it * (it - 1) / 2) --it;
    while (p >= (it + 1) * NT - (it + 1) * it / 2) ++it;
    int jt = it + p - (it * NT - it * (it - 1) / 2);

    int i0 = it * 128, j0 = jt * 128;
    int tid = threadIdx.x, w = tid >> 6, l = tid & 63;
    int wr = w >> 1, wc = w & 1;      // 2x2 wave grid; per-wave output 64x64
    int lc = l & 31, hi = l >> 5;     // 32x32 fragment: row/col = lc, k-group = hi

    __shared__ __align__(16) unsigned char smem[2][16384];   // each: A 8K | B 8K
    __shared__ int fl;

    const unsigned char* XA = Xq + ((size_t)b * HW_ + i0) * C_;
    const unsigned char* XB = Xq + ((size_t)b * HW_ + j0) * C_;

    int rlo = tid >> 2, sl = tid & 3;      // 64 rows x 4 slots of 16 B

    auto stg = [&](unsigned char* buf, int k0) {
#pragma unroll
        for (int q = 0; q < 2; ++q) {
            int R = q * 64 + rlo;
            int gp = sl ^ ((R >> 1) & 3);  // XOR pre-swizzle of global source
            __builtin_amdgcn_global_load_lds(
                (const __attribute__((address_space(1))) void*)(XA + (size_t)R * C_ + k0 + (gp << 4)),
                (__attribute__((address_space(3))) void*)(buf + R * 64 + (sl << 4)), 16, 0, 0);
            __builtin_amdgcn_global_load_lds(
                (const __attribute__((address_space(1))) void*)(XB + (size_t)R * C_ + k0 + (gp << 4)),
                (__attribute__((address_space(3))) void*)(buf + 8192 + R * 64 + (sl << 4)), 16, 0, 0);
        }
    };

    // r = panel row (0..127); reads lane's 32 B (k-group hi) of that row
    auto ldfrag = [&](const unsigned char* base, int r) {
        int sw = (r >> 1) & 3;
        uint4 lo = *(const uint4*)(base + r * 64 + (((hi * 2) ^ sw) << 4));
        uint4 hh = *(const uint4*)(base + r * 64 + (((hi * 2 + 1) ^ sw) << 4));
        int8v v; v[0] = lo.x; v[1] = lo.y; v[2] = lo.z; v[3] = lo.w;
        v[4] = hh.x; v[5] = hh.y; v[6] = hh.z; v[7] = hh.w;
        return v;
    };

    f32x16 acc[2][2];
#pragma unroll
    for (int m = 0; m < 2; ++m)
#pragma unroll
        for (int n = 0; n < 2; ++n)
#pragma unroll
            for (int r = 0; r < 16; ++r) acc[m][n][r] = 0.f;

    // prologue: K-tile 0 -> buf0; drain; sync
    stg(smem[0], 0);
    WAITV0();
    BARRIER();

    for (int kt = 0; kt < 16; ++kt) {
        unsigned char* cur = smem[kt & 1];
        if (kt < 15) stg(smem[(kt + 1) & 1], (kt + 1) * 64);

        int8v bv[2];
#pragma unroll
        for (int n = 0; n < 2; ++n) bv[n] = ldfrag(cur + 8192, wc * 64 + n * 32 + lc);
        __builtin_amdgcn_s_setprio(1);
#pragma unroll
        for (int m = 0; m < 2; ++m) {
            int8v av = ldfrag(cur, wr * 64 + m * 32 + lc);
#pragma unroll
            for (int n = 0; n < 2; ++n)
                acc[m][n] = __builtin_amdgcn_mfma_scale_f32_32x32x64_f8f6f4(
                    av, bv[n], acc[m][n], 0, 0, 0, 0x7f7f7f7f, 0, 0x7f7f7f7f);
        }
        __builtin_amdgcn_s_setprio(0);

        if (kt < 15) WAITV0();
        BARRIER();                    // WAR: next iter's stage may overwrite
    }

    // ---- epilogue: deferred normalization rn_i * rn_j ----
    float rnj[2];
#pragma unroll
    for (int n = 0; n < 2; ++n)
        rnj[n] = rn[b * HW_ + j0 + wc * 64 + n * 32 + lc];

    bool any = false;
#pragma unroll
    for (int m = 0; m < 2; ++m)
#pragma unroll
        for (int reg = 0; reg < 16; ++reg) {
            int rr = (reg & 3) + 4 * hi + 8 * (reg >> 2);
            float rni = rn[b * HW_ + i0 + wr * 64 + m * 32 + rr];
#pragma unroll
            for (int n = 0; n < 2; ++n) {
                acc[m][n][reg] *= rni * rnj[n];
                any |= (acc[m][n][reg] >= 0.5f);
            }
        }

    if (tid == 0) fl = 0;
    __syncthreads();
    unsigned long long bal = __ballot(any);
    if (l == 0 && bal != 0ull) atomicOr(&fl, 1);
    __syncthreads();
    bool mirror = (it != jt);
    if (tid == 0) {
        flags[(b * NT + it) * NT + jt] = fl;
        if (mirror) flags[(b * NT + jt) * NT + it] = fl;
    }

    if (fl) {
        size_t affb = (size_t)b * HW_ * HW_;
        float csn[2] = {0.f, 0.f};

#pragma unroll
        for (int m = 0; m < 2; ++m) {
            float rs[16];
#pragma unroll
            for (int r = 0; r < 16; ++r) rs[r] = 0.f;

#pragma unroll
            for (int n = 0; n < 2; ++n) {
                int j = j0 + wc * 64 + n * 32 + lc;
#pragma unroll
                for (int reg = 0; reg < 16; ++reg) {
                    float v = acc[m][n][reg];
                    v = fminf(fmaxf(v, 0.01f), 0.999f);
                    v = (v < 0.5f) ? 0.0f : v;
                    bf16 bb = __float2bfloat16(v);
                    int rr = (reg & 3) + 4 * hi + 8 * (reg >> 2);
                    int i = i0 + wr * 64 + m * 32 + rr;
                    aff[affb + (size_t)i * HW_ + j] = bb;
                    float bf = __bfloat162float(bb);
                    csn[n] += bf;
                    rs[reg] += bf;
                    if (mirror) aff[affb + (size_t)j * HW_ + i] = bb;
                }
            }
            if (mirror) {
#pragma unroll
                for (int reg = 0; reg < 16; ++reg) {
                    float s = rs[reg];
                    s += __shfl_xor(s, 1);
                    s += __shfl_xor(s, 2);
                    s += __shfl_xor(s, 4);
                    s += __shfl_xor(s, 8);
                    s += __shfl_xor(s, 16);
                    if (lc == 0) {
                        int rr = (reg & 3) + 4 * hi + 8 * (reg >> 2);
                        atomicAdd(&colsum[b * HW_ + i0 + wr * 64 + m * 32 + rr], s);
                    }
                }
            }
        }
#pragma unroll
        for (int n = 0; n < 2; ++n) {
            float cs = csn[n];
            cs += __shfl_xor(cs, 32);
            if (hi == 0) atomicAdd(&colsum[b * HW_ + j0 + wc * 64 + n * 32 + lc], cs);
        }
    }
}

// ---- kernel 3: BOTH propagation rounds fused (pcm = 2) ---------------------
__global__ __launch_bounds__(256) void kprop2(const float* __restrict__ lf, const bf16* __restrict__ aff,
                                              const int* __restrict__ flags, const float* __restrict__ colsum,
                                              float* __restrict__ outp) {
    int jt = blockIdx.x, b = blockIdx.y;       // 32 tiles of 128 cols
    int t = threadIdx.x;
    int q = t >> 7, jl = t & 127;              // 2-way row-range split
    int j = jt * 128 + jl;
    __shared__ float lfs[NK * 128];            // staged lf rows / q=1 partials
    __shared__ float lf1t[NK * 128];           // recomputed lf1 i-tile (f32)

    float oacc[NK];
#pragma unroll
    for (int k = 0; k < NK; ++k) oacc[k] = 0.f;

    for (int it = 0; it < NT; ++it) {
        if (flags[(b * NT + it) * NT + jt] == 0) continue;   // block-uniform

        // ---- pass 1: build lf1 for i-tile 'it' ----
        float racc[NK];
#pragma unroll
        for (int k = 0; k < NK; ++k) racc[k] = 0.f;

        for (int ht = 0; ht < NT; ++ht) {
            if (flags[(b * NT + ht) * NT + it] == 0) continue;   // block-uniform
            __syncthreads();                   // protect lfs from prev readers
            for (int idx = t; idx < NK * 128; idx += 256)
                lfs[idx] = lf[((size_t)b * NK + (idx >> 7)) * HW_ + ht * 128 + (idx & 127)];
            __syncthreads();
            const bf16* ap = aff + ((size_t)b * HW_ + ht * 128 + q * 64) * HW_ + it * 128 + jl;
            for (int ii = 0; ii < 64; ii += 4) {
                float a0 = __bfloat162float(ap[(size_t)(ii + 0) * HW_]);
                float a1 = __bfloat162float(ap[(size_t)(ii + 1) * HW_]);
                float a2 = __bfloat162float(ap[(size_t)(ii + 2) * HW_]);
                float a3 = __bfloat162float(ap[(size_t)(ii + 3) * HW_]);
                int base = q * 64 + ii;
#pragma unroll
                for (int k = 0; k < NK; ++k)
                    racc[k] = fmaf(lfs[(k << 7) + base + 0], a0,
                               fmaf(lfs[(k << 7) + base + 1], a1,
                               fmaf(lfs[(k << 7) + base + 2], a2,
                               fmaf(lfs[(k << 7) + base + 3], a3, racc[k]))));
            }
        }
        __syncthreads();                       // lfs free; prev lf1t readers done
        if (q == 1) {
#pragma unroll
            for (int k = 0; k < NK; ++k) lfs[(k << 7) + jl] = racc[k];
        }
        __syncthreads();
        if (q == 0) {
            float invi = 1.0f / colsum[b * HW_ + it * 128 + jl];
#pragma unroll
            for (int k = 0; k < NK; ++k)
                lf1t[(k << 7) + jl] = (racc[k] + lfs[(k << 7) + jl]) * invi;
        }
        __syncthreads();

        // ---- pass 2: out += lf1t * aff[it -> jt] ----
        const bf16* ap2 = aff + ((size_t)b * HW_ + it * 128 + q * 64) * HW_ + j;
        for (int ii = 0; ii < 64; ii += 4) {
            float a0 = __bfloat162float(ap2[(size_t)(ii + 0) * HW_]);
            float a1 = __bfloat162float(ap2[(size_t)(ii + 1) * HW_]);
            float a2 = __bfloat162float(ap2[(size_t)(ii + 2) * HW_]);
            float a3 = __bfloat162float(ap2[(size_t)(ii + 3) * HW_]);
            int base = q * 64 + ii;
#pragma unroll
            for (int k = 0; k < NK; ++k)
                oacc[k] = fmaf(lf1t[(k << 7) + base + 0], a0,
                           fmaf(lf1t[(k << 7) + base + 1], a1,
                           fmaf(lf1t[(k << 7) + base + 2], a2,
                           fmaf(lf1t[(k << 7) + base + 3], a3, oacc[k]))));
        }
    }

    __syncthreads();
    if (q == 1) {
#pragma unroll
        for (int k = 0; k < NK; ++k) lfs[(k << 7) + jl] = oacc[k];
    }
    __syncthreads();
    if (q == 0) {
        float inv = 1.0f / colsum[b * HW_ + j];
#pragma unroll
        for (int k = 0; k < NK; ++k)
            outp[((size_t)b * NK + k) * HW_ + j] = (oacc[k] + lfs[(k << 7) + jl]) * inv;
    }
}

extern "C" void kernel_launch(void* const* d_in, const int* in_sizes, int n_in,
                              void* d_out, int out_size, void* d_ws, size_t ws_size,
                              hipStream_t stream) {
    const float* x4 = (const float*)d_in[0];
    const float* logits = (const float*)d_in[1];
    float* out = (float*)d_out;

    char* w = (char*)d_ws;
    size_t off = 0;
    auto take = [&](size_t bytes) {
        char* p = w + off;
        off += (bytes + 255) & ~(size_t)255;
        return p;
    };
    unsigned char* Xq = (unsigned char*)take((size_t)B_ * HW_ * C_);    // 32 MiB
    bf16* aff     = (bf16*)take((size_t)B_ * HW_ * HW_ * 2);            // 256 MiB
    float* colsum = (float*)take((size_t)B_ * HW_ * 4);
    int*   flags  = (int*)take((size_t)B_ * NT * NT * 4);
    float* rn     = (float*)take((size_t)B_ * HW_ * 4);

    // 3 launches: ktrans zeroes colsum; kgram writes flags densely.
    ktrans<<<dim3(64, B_), dim3(256), 0, stream>>>(x4, rn, Xq, colsum);
    kgram <<<dim3(NTRI * B_), dim3(256), 0, stream>>>(Xq, rn, aff, colsum, flags);
    kprop2<<<dim3(NT, B_), dim3(256), 0, stream>>>(logits, aff, flags, colsum, out);
}